// Round 10
// baseline (274.146 us; speedup 1.0000x reference)
//
#include <hip/hip_runtime.h>
#include <math.h>

#define NN 50000
#define E0 640000
#define ET 690000   // E0 + NN self loops
#define F1 128
#define D1 256      // 8 heads * 32
#define C2 16
#define NB 196      // ceil(NN/256)
#define MPAD 50048  // 391*128, padded node count for MFMA tiles
#define PADK 136    // 128 + 8 pad (breaks ds_read_b128 bank conflicts)
#define LOG2E 1.4426950408889634f
#define NBK1 782    // ceil(NN/64) node-blocks for agg1

typedef _Float16 f16x8 __attribute__((ext_vector_type(8)));
typedef _Float16 h2 __attribute__((ext_vector_type(2)));
typedef __attribute__((ext_vector_type(4))) float f32x4;

__device__ __forceinline__ unsigned short f2h(float f) {
  union { _Float16 h; unsigned short u; } c;
  c.h = (_Float16)f;
  return c.u;
}
__device__ __forceinline__ float h2f(unsigned short u) {
  union { unsigned short u; _Float16 h; } c; c.u = u; return (float)c.h;
}
__device__ __forceinline__ h2 u2h2(unsigned u) {
  union { unsigned u; h2 h; } c; c.u = u; return c.h;
}
__device__ __forceinline__ unsigned h22u(h2 h) {
  union { h2 h; unsigned u; } c; c.h = h; return c.u;
}

// DPP-based lane-group sums: v_add_f32 with DPP modifier, no DS ops.
// 0xB1 = quad_perm [1,0,3,2] (xor 1), 0x4E = quad_perm [2,3,0,1] (xor 2).
template <int CTRL>
__device__ __forceinline__ float dpp_add(float c) {
  int t = __builtin_amdgcn_update_dpp(0, __builtin_bit_cast(int, c), CTRL, 0xF, 0xF, true);
  return c + __builtin_bit_cast(float, t);
}
// Broadcast lane K of each quad to all 4 lanes of the quad (quad_perm K,K,K,K).
template <int K>
__device__ __forceinline__ int dpp_bcast(int v) {
  constexpr int ctrl = K | (K << 2) | (K << 4) | (K << 6);
  return __builtin_amdgcn_update_dpp(0, v, ctrl, 0xF, 0xF, true);
}

// ---------------- prep: weight converts + degree histogram ----------------
// blocks [0,256): wt | [256,288): wt2 | rest: edge histogram.
__global__ __launch_bounds__(256) void k_prep(
    const float* __restrict__ Wl, const float* __restrict__ Wr,
    const float* __restrict__ W2l, const float* __restrict__ W2r,
    const int* __restrict__ ei,
    unsigned short* __restrict__ wt, unsigned short* __restrict__ wt2,
    int* __restrict__ deg) {
  const int b = blockIdx.x;
  if (b < 256) {
    int tid = b * 256 + threadIdx.x;            // = n*128 + k
    int n = tid >> 7, k = tid & 127;
    float v = (n < 256) ? Wl[k * 256 + n] : Wr[k * 256 + (n - 256)];
    wt[tid] = f2h(v);
  } else if (b < 288) {
    int tid = (b - 256) * 256 + threadIdx.x;    // = n*256 + k
    int n = tid >> 8, k = tid & 255;
    float v = (n < 16) ? W2l[k * 16 + n] : W2r[k * 16 + (n - 16)];
    wt2[tid] = f2h(v);
  } else {
    int e = (b - 288) * 256 + threadIdx.x;
    if (e >= ET) return;
    int d = (e < E0) ? ei[E0 + e] : (e - E0);
    atomicAdd(&deg[d], 1);
  }
}

// ---------------- Layer-1 GEMM via MFMA (fp16) ----------------
// A-tile (64 rows) staged ONCE in LDS (f32->f16 convert once); R10: B
// fragments loaded DIRECT from global wt (131 KB, L2-resident). Removes the
// per-panel Bl restage: 8 barriers/block -> 1, LDS 52->17.4 KB -> ~8
// blocks/CU (vs 3) so B-load latency hides under TLP instead of serializing
// the whole block at each panel barrier. (Single-variable change vs R9;
// R7's direct-B regression was confounded with its T-transpose epilogue.)
// R9 operand-swap epilogue kept: D = Wt_frag . x_frag -> lane holds 4
// consecutive wt-cols at one node -> one aligned 8B uint2 store per (i,j).
// Outputs HEAD-MAJOR: out[head][node][32].
__global__ __launch_bounds__(256) void k_gemm1m(
    const float* __restrict__ x, const unsigned short* __restrict__ wt,
    unsigned short* __restrict__ xlh, unsigned short* __restrict__ xrh) {
  __shared__ unsigned short Al[64 * PADK];
  const int t = threadIdx.x;
  const int m0 = blockIdx.x * 64;
  {
    const int r = t >> 4;             // 0..15
    const int c = (t & 15) * 8;
#pragma unroll
    for (int p = 0; p < 4; ++p) {
      const int row = r + p * 16;
      const int rg = m0 + row;
      const float* xp = &x[(size_t)(rg < NN ? rg : NN - 1) * F1 + c];
      float4 lo = *(const float4*)xp;
      float4 hi = *(const float4*)(xp + 4);
      h2 q0 = h2{(_Float16)lo.x, (_Float16)lo.y};
      h2 q1 = h2{(_Float16)lo.z, (_Float16)lo.w};
      h2 q2 = h2{(_Float16)hi.x, (_Float16)hi.y};
      h2 q3 = h2{(_Float16)hi.z, (_Float16)hi.w};
      uint4 st; st.x = h22u(q0); st.y = h22u(q1); st.z = h22u(q2); st.w = h22u(q3);
      *(uint4*)&Al[row * PADK + c] = st;
    }
  }
  __syncthreads();
  const int wave = t >> 6, lane = t & 63;
  const int mw = (wave >> 1) * 32, nw = (wave & 1) * 64;
  const int fr = lane & 15, fq = lane >> 4;
  for (int ny = 0; ny < 4; ++ny) {
    const int n0 = ny * 128;
    f32x4 acc[2][4] = {};
#pragma unroll
    for (int ks = 0; ks < 4; ++ks) {
      const int ko = ks * 32 + fq * 8;
      f16x8 a[2], b[4];
#pragma unroll
      for (int i = 0; i < 2; ++i)
        a[i] = *(const f16x8*)&Al[(mw + i * 16 + fr) * PADK + ko];
#pragma unroll
      for (int j = 0; j < 4; ++j)
        b[j] = *(const f16x8*)&wt[(size_t)(n0 + nw + j * 16 + fr) * F1 + ko];
      // operand swap: D = b (A-op, rows = wt cols) x a (B-op, cols = nodes)
#pragma unroll
      for (int i = 0; i < 2; ++i)
#pragma unroll
        for (int j = 0; j < 4; ++j)
          acc[i][j] = __builtin_amdgcn_mfma_f32_16x16x32_f16(b[j], a[i], acc[i][j], 0, 0, 0);
    }
    unsigned short* outp = (n0 < 256) ? xlh : xrh;
#pragma unroll
    for (int j = 0; j < 4; ++j) {
      const int col0 = (n0 & 255) + nw + j * 16 + fq * 4;  // 4 consecutive cols
      const int head = col0 >> 5, f = col0 & 31;           // 4-aligned within head
      unsigned short* hp = outp + (size_t)head * NN * 32 + f;
#pragma unroll
      for (int i = 0; i < 2; ++i) {
        const int gm = m0 + mw + i * 16 + fr;              // one node per lane
        if (gm < NN) {
          h2 lo = h2{(_Float16)acc[i][j][0], (_Float16)acc[i][j][1]};
          h2 hi = h2{(_Float16)acc[i][j][2], (_Float16)acc[i][j][3]};
          uint2 st; st.x = h22u(lo); st.y = h22u(hi);
          *(uint2*)&hp[(size_t)gm * 32] = st;              // 8B aligned store
        }
      }
    }
  }
}

// ---------------- CSR scan ----------------
__global__ __launch_bounds__(256) void k_scan_part(const int* __restrict__ deg,
                                                   int* __restrict__ part) {
  int i = blockIdx.x * 256 + threadIdx.x;
  int v = (i < NN) ? deg[i] : 0;
  v += __shfl_xor(v, 1);  v += __shfl_xor(v, 2);  v += __shfl_xor(v, 4);
  v += __shfl_xor(v, 8);  v += __shfl_xor(v, 16); v += __shfl_xor(v, 32);
  __shared__ int w[4];
  if ((threadIdx.x & 63) == 0) w[threadIdx.x >> 6] = v;
  __syncthreads();
  if (threadIdx.x == 0) part[blockIdx.x] = w[0] + w[1] + w[2] + w[3];
}

// Block-local scan + inline prefix over part[0..b).
// Emits: offs[] (for agg2), cursor deg[i]=beg+1 (slot 0 = self-loop,
// pre-placed csr[beg]=i, coalesced since excl is monotone in i), and
// NATURAL-ORDER packed metadata ninfo[i] = {beg, i|deg<<16} so agg1's
// prologue is ONE load level.
__global__ __launch_bounds__(256) void k_scan_apply(int* __restrict__ deg,
                                                    const int* __restrict__ part,
                                                    int* __restrict__ offs,
                                                    uint2* __restrict__ ninfo,
                                                    unsigned short* __restrict__ csr) {
  __shared__ int lds[256];
  __shared__ int red[4];
  const int b = blockIdx.x, t = threadIdx.x;
  const int i = b * 256 + t;
  int v = (i < NN) ? deg[i] : 0;
  lds[t] = v;
  // prefix of preceding blocks' partial sums
  int pp = 0;
  for (int j = t; j < b; j += 256) pp += part[j];
  pp += __shfl_xor(pp, 1);  pp += __shfl_xor(pp, 2);  pp += __shfl_xor(pp, 4);
  pp += __shfl_xor(pp, 8);  pp += __shfl_xor(pp, 16); pp += __shfl_xor(pp, 32);
  if ((t & 63) == 0) red[t >> 6] = pp;
  __syncthreads();
  const int prefix = red[0] + red[1] + red[2] + red[3];
  for (int off = 1; off < 256; off <<= 1) {
    int u = (t >= off) ? lds[t - off] : 0;
    __syncthreads();
    lds[t] += u;
    __syncthreads();
  }
  int excl = prefix + lds[t] - v;
  if (i < NN) {
    offs[i] = excl;
    deg[i] = excl + 1;                  // cursor: slot 0 is the self-loop
    csr[excl] = (unsigned short)i;      // self-loop pre-placed
    ninfo[i] = make_uint2((unsigned)excl, (unsigned)i | ((unsigned)v << 16));
  }
  if (b == NB - 1 && t == 255) offs[NN] = prefix + lds[255];
}

// Real edges only (self-loops pre-placed by scan_apply).
__global__ void k_scatter(const int* __restrict__ ei, int* __restrict__ cur,
                          unsigned short* __restrict__ csr) {
  int e = blockIdx.x * 256 + threadIdx.x;
  if (e >= E0) return;
  int s = ei[e], d = ei[E0 + e];
  int pos = atomicAdd(&cur[d], 1);
  csr[pos] = (unsigned short)s;   // node ids < 65536
}

// ---------------- Layer-1 aggregation (head-pinned, 16 nodes/wave) ----------------
// head = blockIdx&7 pins each head's 3.2 MB slice to one XCD L2 (FETCH ~58 MB
// = compulsory). One wave = 16 nodes x 1 head; each 4-lane group owns one
// node's edge loop; p group-uniform -> no epilogue reduction.
// Prologue: ONE ninfo load gives {beg, deg}. Pipeline: csr ids lane-split
// two quads ahead; ids broadcast via DPP quad_perm; XL gathers one quad
// ahead. Tail via cndmask masking (p=0).
__global__ __launch_bounds__(256) void k_agg1(
    const unsigned short* __restrict__ xlh, const unsigned short* __restrict__ xrh,
    unsigned short* __restrict__ hb,
    const uint2* __restrict__ ninfo, const unsigned short* __restrict__ csr,
    const float* __restrict__ att, const float* __restrict__ b1) {
  const int b = blockIdx.x;
  const int head = b & 7;
  const int wave = threadIdx.x >> 6;
  const int lane = threadIdx.x & 63;
  const int g = lane >> 2;          // node group 0..15
  const int j4 = lane & 3;          // lane within group
  const int idxn = (b >> 3) * 64 + wave * 16 + g;
  const bool valid = idxn < NN;
  const int n = valid ? idxn : 0;
  const int colh = j4 * 8;          // feat offset within head
  const int col = head * 32 + colh; // global feat col (att/b1)
  const unsigned short* xlhead = xlh + (size_t)head * NN * 32;

  const uint2 nf = ninfo[n];
  const int beg = (int)nf.x;
  const int fin = valid ? beg + (int)(nf.y >> 16) : beg;

  const uint4 xru = *(const uint4*)&xrh[((size_t)head * NN + n) * 32 + colh];
  h2 xr2[4];
  xr2[0] = u2h2(xru.x); xr2[1] = u2h2(xru.y);
  xr2[2] = u2h2(xru.z); xr2[3] = u2h2(xru.w);
  float at8[8];
  *(float4*)&at8[0] = *(const float4*)&att[col];
  *(float4*)&at8[4] = *(const float4*)&att[col + 4];
  h2 ath6[4], ath4[4];
#pragma unroll
  for (int j = 0; j < 4; ++j) {
    ath6[j] = h2{(_Float16)(at8[2 * j] * (0.6f * LOG2E)),
                 (_Float16)(at8[2 * j + 1] * (0.6f * LOG2E))};
    ath4[j] = h2{(_Float16)(at8[2 * j] * (0.4f * LOG2E)),
                 (_Float16)(at8[2 * j + 1] * (0.4f * LOG2E))};
  }
  float l = 0.f;
  h2 acc2[4] = {h2{0, 0}, h2{0, 0}, h2{0, 0}, h2{0, 0}};

  // lane-split id load: lane j4 fetches csr[base+j4], clamped into [beg,fin)
  auto ldids = [&](int base) -> int {
    int a = base + j4;
    a = (a < fin) ? a : beg;      // empty groups read csr[beg] (self-loop)
    return (int)csr[a];
  };
  auto XLrow = [&](int s) -> uint4 {
    return *(const uint4*)&xlhead[(size_t)s * 32 + colh];
  };
  auto edge = [&](const uint4& w, bool live) {
    h2 xh[4];
    xh[0] = u2h2(w.x); xh[1] = u2h2(w.y); xh[2] = u2h2(w.z); xh[3] = u2h2(w.w);
    float cv = 0.f, ca = 0.f;
#pragma unroll
    for (int j = 0; j < 4; ++j) {
      h2 v = xh[j] + xr2[j];
      h2 a = u2h2(h22u(v) & 0x7FFF7FFFu);       // |v| per half
      cv = __builtin_amdgcn_fdot2(v, ath6[j], cv, false);
      ca = __builtin_amdgcn_fdot2(a, ath4[j], ca, false);
    }
    float c = cv + ca;
    c = dpp_add<0xB1>(c);             // + lane^1 (quad_perm, no DS op)
    c = dpp_add<0x4E>(c);             // + lane^2 -> group total in all 4 lanes
    float p = exp2f(c);
    p = live ? p : 0.f;
    l += p;
    const _Float16 ph = (_Float16)p;
    const h2 p2 = h2{ph, ph};
#pragma unroll
    for (int j = 0; j < 4; ++j) acc2[j] += p2 * xh[j];
  };

  // software pipeline: w = quad idx, ids1 = ids for quad idx+4
  int ids = ldids(beg);
  uint4 w0 = XLrow(dpp_bcast<0>(ids));
  uint4 w1 = XLrow(dpp_bcast<1>(ids));
  uint4 w2 = XLrow(dpp_bcast<2>(ids));
  uint4 w3 = XLrow(dpp_bcast<3>(ids));
  int ids1 = ldids(beg + 4);
  for (int idx = beg; idx < fin; idx += 4) {
    const uint4 v0 = XLrow(dpp_bcast<0>(ids1));   // gathers for quad idx+4
    const uint4 v1 = XLrow(dpp_bcast<1>(ids1));
    const uint4 v2 = XLrow(dpp_bcast<2>(ids1));
    const uint4 v3 = XLrow(dpp_bcast<3>(ids1));
    const int ids2 = ldids(idx + 8);              // ids for quad idx+8
    edge(w0, true);                               // idx < fin by loop cond
    edge(w1, idx + 1 < fin);
    edge(w2, idx + 2 < fin);
    edge(w3, idx + 3 < fin);
    w0 = v0; w1 = v1; w2 = v2; w3 = v3; ids1 = ids2;
  }

  if (valid) {
    const float rl = __builtin_amdgcn_rcpf(l + 1e-16f);
    float b8[8], o[8];
    *(float4*)&b8[0] = *(const float4*)&b1[col];
    *(float4*)&b8[4] = *(const float4*)&b1[col + 4];
#pragma unroll
    for (int j = 0; j < 4; ++j) {
      o[2 * j]     = (float)acc2[j][0] * rl + b8[2 * j];
      o[2 * j + 1] = (float)acc2[j][1] * rl + b8[2 * j + 1];
    }
#pragma unroll
    for (int k = 0; k < 8; ++k)
      o[k] = o[k] > 0.f ? o[k] : exp2f(o[k] * LOG2E) - 1.f;  // cheap ELU
    ushort4 p;
    p.x = f2h(o[0]); p.y = f2h(o[1]); p.z = f2h(o[2]); p.w = f2h(o[3]);
    ushort4 q;
    q.x = f2h(o[4]); q.y = f2h(o[5]); q.z = f2h(o[6]); q.w = f2h(o[7]);
    uint4 packed;
    packed.x = *(unsigned*)&p.x; packed.y = *(unsigned*)&p.z;
    packed.z = *(unsigned*)&q.x; packed.w = *(unsigned*)&q.z;
    *(uint4*)&hb[(size_t)n * D1 + col] = packed;
  }
}

// ---------------- Layer-2 GEMM via MFMA (fp16, no LDS) ----------------
// h2[50000, 32] = hb @ Wt2^T. B fragments direct from global (wt2 is 16 KB,
// L1-resident). No barrier.
__global__ __launch_bounds__(256) void k_gemm2m(
    const unsigned short* __restrict__ hb, const unsigned short* __restrict__ wt2,
    unsigned short* __restrict__ h2lh, float* __restrict__ h2r) {
  const int t = threadIdx.x;
  const int wave = t >> 6, lane = t & 63;
  const int fr = lane & 15, fq = lane >> 4;
  const int m0 = blockIdx.x * 128 + wave * 32;
  f32x4 acc[2][2] = {};
#pragma unroll
  for (int ks = 0; ks < 8; ++ks) {
    const int ko = ks * 32 + fq * 8;
    f16x8 a[2], b[2];
#pragma unroll
    for (int i = 0; i < 2; ++i) {
      int row = m0 + i * 16 + fr; if (row >= NN) row = NN - 1;
      a[i] = *(const f16x8*)&hb[(size_t)row * D1 + ko];
    }
#pragma unroll
    for (int j = 0; j < 2; ++j)
      b[j] = *(const f16x8*)&wt2[(j * 16 + fr) * 256 + ko];
#pragma unroll
    for (int i = 0; i < 2; ++i)
#pragma unroll
      for (int j = 0; j < 2; ++j)
        acc[i][j] = __builtin_amdgcn_mfma_f32_16x16x32_f16(a[i], b[j], acc[i][j], 0, 0, 0);
  }
#pragma unroll
  for (int i = 0; i < 2; ++i) {
    const int gm0 = m0 + i * 16 + fq * 4;
#pragma unroll
    for (int r = 0; r < 4; ++r) {
      const int gm = gm0 + r;
      if (gm < NN) {
        h2lh[(size_t)gm * C2 + fr] = f2h(acc[i][0][r]);
        h2r[(size_t)gm * C2 + fr] = acc[i][1][r];
      }
    }
  }
}

// ---------------- Layer-2 aggregation ----------------
// Unrolled 2-wide (8 edges/wave-iter) so both gathers are in flight together.
__global__ __launch_bounds__(256) void k_agg2(
    const unsigned short* __restrict__ h2lh, const float* __restrict__ h2r,
    const int* __restrict__ offs, const unsigned short* __restrict__ csr,
    const float* __restrict__ att2, const float* __restrict__ b2,
    float* __restrict__ out) {
  const int wave = threadIdx.x >> 6;
  const int lane = threadIdx.x & 63;
  const int n = blockIdx.x * 4 + wave;
  if (n >= NN) return;
  const int c = lane & 15, g = lane >> 4;
  const float xr_v = h2r[(size_t)n * C2 + c];
  const float att_v = att2[c] * LOG2E;
  float l = 0.f, acc = 0.f;
  const int beg = offs[n], fin = offs[n + 1];
  for (int idx = beg + g; idx < fin; idx += 8) {
    const int i1 = idx + 4;
    const bool m1 = i1 < fin;
    const int s0 = csr[idx];
    const int s1 = csr[m1 ? i1 : idx];
    const float xl0 = h2f(h2lh[(size_t)s0 * C2 + c]);
    const float xl1 = h2f(h2lh[(size_t)s1 * C2 + c]);
    float v0 = xl0 + xr_v; v0 = fmaxf(v0, 0.2f * v0);
    float v1 = xl1 + xr_v; v1 = fmaxf(v1, 0.2f * v1);
    float sc0 = v0 * att_v, sc1 = v1 * att_v;
    sc0 = dpp_add<0xB1>(sc0);   sc1 = dpp_add<0xB1>(sc1);
    sc0 = dpp_add<0x4E>(sc0);   sc1 = dpp_add<0x4E>(sc1);
    sc0 = dpp_add<0x124>(sc0);  sc1 = dpp_add<0x124>(sc1);
    sc0 = dpp_add<0x128>(sc0);  sc1 = dpp_add<0x128>(sc1);
    const float p0 = exp2f(sc0);
    const float p1 = m1 ? exp2f(sc1) : 0.f;
    l += p0 + p1;
    acc = fmaf(p0, xl0, fmaf(p1, xl1, acc));
  }
  l += __shfl_xor(l, 16);   l += __shfl_xor(l, 32);
  acc += __shfl_xor(acc, 16); acc += __shfl_xor(acc, 32);
  float o = acc * __builtin_amdgcn_rcpf(l + 1e-16f) + b2[c];
  o = o > 0.f ? o : 0.01f * o;
  if (lane < 16) out[(size_t)n * C2 + c] = o;
}

extern "C" void kernel_launch(void* const* d_in, const int* in_sizes, int n_in,
                              void* d_out, int out_size, void* d_ws, size_t ws_size,
                              hipStream_t stream) {
  const float* x    = (const float*)d_in[0];
  const int*   ei   = (const int*)d_in[1];
  const float* W1l  = (const float*)d_in[2];
  const float* W1r  = (const float*)d_in[3];
  const float* att1 = (const float*)d_in[4];
  const float* b1   = (const float*)d_in[5];
  const float* W2l  = (const float*)d_in[6];
  const float* W2r  = (const float*)d_in[7];
  const float* att2 = (const float*)d_in[8];
  const float* b2   = (const float*)d_in[9];
  float* out = (float*)d_out;

  // Workspace layout (~79.3 MB):
  unsigned short* xlh = (unsigned short*)d_ws;        // [8][NN][32] fp16
  unsigned short* xrh = xlh + (size_t)NN * D1;        // [8][NN][32] fp16
  unsigned short* hb  = xrh + (size_t)NN * D1;        // [NN][256] fp16
  int* deg  = (int*)(hb + (size_t)NN * D1);           // NN (becomes cursor)
  int* part = deg + NN;                               // NB
  int* offs = part + NB;                              // NN+1 (+1 pad for align)
  uint2* ninfo = (uint2*)(offs + NN + 2);             // NN {beg, n|deg<<16}
  unsigned short* csr = (unsigned short*)(ninfo + NN);  // ET u16
  unsigned short* wt  = csr + ET + 2;                 // 512*128 fp16
  unsigned short* wt2 = wt + 512 * F1;                // 32*256 fp16
  unsigned short* h2lh = xlh;                         // alias: xlh dead after agg1
  float* h2r = (float*)(h2lh + (size_t)NN * C2);

  hipMemsetAsync(deg, 0, NN * sizeof(int), stream);
  k_prep<<<288 + (ET + 255) / 256, 256, 0, stream>>>(
      W1l, W1r, W2l, W2r, ei, wt, wt2, deg);
  k_gemm1m<<<MPAD / 64, 256, 0, stream>>>(x, wt, xlh, xrh);
  k_scan_part<<<NB, 256, 0, stream>>>(deg, part);
  k_scan_apply<<<NB, 256, 0, stream>>>(deg, part, offs, ninfo, csr);
  k_scatter<<<(E0 + 255) / 256, 256, 0, stream>>>(ei, deg, csr);
  k_agg1<<<NBK1 * 8, 256, 0, stream>>>(xlh, xrh, hb, ninfo, csr, att1, b1);
  k_gemm2m<<<(NN + 127) / 128, 256, 0, stream>>>(hb, wt2, h2lh, h2r);
  k_agg2<<<NN / 4, 256, 0, stream>>>(h2lh, h2r, offs, csr, att2, b2, out);
}

// Round 12
// 256.219 us; speedup vs baseline: 1.0700x; 1.0700x over previous
//
#include <hip/hip_runtime.h>
#include <math.h>

#define NN 50000
#define E0 640000
#define ET 690000   // E0 + NN self loops
#define F1 128
#define D1 256      // 8 heads * 32
#define C2 16
#define NB 196      // ceil(NN/256)
#define MPAD 50048  // 391*128, padded node count for MFMA tiles
#define PADK 136    // 128 + 8 pad (breaks ds_read_b128 bank conflicts)
#define LOG2E 1.4426950408889634f
#define NBK1 782    // ceil(NN/64) node-blocks for agg1

typedef _Float16 f16x8 __attribute__((ext_vector_type(8)));
typedef _Float16 h2 __attribute__((ext_vector_type(2)));
typedef __attribute__((ext_vector_type(4))) float f32x4;

__device__ __forceinline__ unsigned short f2h(float f) {
  union { _Float16 h; unsigned short u; } c;
  c.h = (_Float16)f;
  return c.u;
}
__device__ __forceinline__ float h2f(unsigned short u) {
  union { unsigned short u; _Float16 h; } c; c.u = u; return (float)c.h;
}
__device__ __forceinline__ h2 u2h2(unsigned u) {
  union { unsigned u; h2 h; } c; c.u = u; return c.h;
}
__device__ __forceinline__ unsigned h22u(h2 h) {
  union { h2 h; unsigned u; } c; c.h = h; return c.u;
}

// DPP-based lane-group sums: v_add_f32 with DPP modifier, no DS ops.
// 0xB1 = quad_perm [1,0,3,2] (xor 1), 0x4E = quad_perm [2,3,0,1] (xor 2).
template <int CTRL>
__device__ __forceinline__ float dpp_add(float c) {
  int t = __builtin_amdgcn_update_dpp(0, __builtin_bit_cast(int, c), CTRL, 0xF, 0xF, true);
  return c + __builtin_bit_cast(float, t);
}
// Broadcast lane K of each quad to all 4 lanes of the quad (quad_perm K,K,K,K).
template <int K>
__device__ __forceinline__ int dpp_bcast(int v) {
  constexpr int ctrl = K | (K << 2) | (K << 4) | (K << 6);
  return __builtin_amdgcn_update_dpp(0, v, ctrl, 0xF, 0xF, true);
}

// ---------------- prep: weight converts + degree histogram ----------------
// blocks [0,256): wt | [256,288): wt2 | rest: edge histogram.
__global__ __launch_bounds__(256) void k_prep(
    const float* __restrict__ Wl, const float* __restrict__ Wr,
    const float* __restrict__ W2l, const float* __restrict__ W2r,
    const int* __restrict__ ei,
    unsigned short* __restrict__ wt, unsigned short* __restrict__ wt2,
    int* __restrict__ deg) {
  const int b = blockIdx.x;
  if (b < 256) {
    int tid = b * 256 + threadIdx.x;            // = n*128 + k
    int n = tid >> 7, k = tid & 127;
    float v = (n < 256) ? Wl[k * 256 + n] : Wr[k * 256 + (n - 256)];
    wt[tid] = f2h(v);
  } else if (b < 288) {
    int tid = (b - 256) * 256 + threadIdx.x;    // = n*256 + k
    int n = tid >> 8, k = tid & 255;
    float v = (n < 16) ? W2l[k * 16 + n] : W2r[k * 16 + (n - 16)];
    wt2[tid] = f2h(v);
  } else {
    int e = (b - 288) * 256 + threadIdx.x;
    if (e >= ET) return;
    int d = (e < E0) ? ei[E0 + e] : (e - E0);
    atomicAdd(&deg[d], 1);
  }
}

// ---------------- Layer-1 GEMM via MFMA (fp16) ----------------
// R9-proven bones: A-tile (64 rows) staged ONCE; B staged through LDS
// (load-bearing — R10's direct-B cost +20us); swap-epilogue (lane holds 4
// consecutive wt-cols at one node -> one aligned 8B uint2 store).
// R11 increment: Bl DOUBLE-BUFFERED at 64-col half-panels. stage(hp+1) into
// the alternate buffer is issued BEFORE compute(hp), so global->LDS staging
// latency overlaps MFMA; 1 barrier per half-panel (8 total, same count as
// R9 but each with staging work in flight). LDS = 17.4 + 2x17.4 = 52.2 KB
// -> 3 blocks/CU (unchanged vs R9).
// Outputs HEAD-MAJOR: out[head][node][32].
__global__ __launch_bounds__(256) void k_gemm1m(
    const float* __restrict__ x, const unsigned short* __restrict__ wt,
    unsigned short* __restrict__ xlh, unsigned short* __restrict__ xrh) {
  __shared__ unsigned short Al[64 * PADK];
  __shared__ unsigned short Bl0[64 * PADK];
  __shared__ unsigned short Bl1[64 * PADK];
  const int t = threadIdx.x;
  const int m0 = blockIdx.x * 64;
  const int rS = t >> 4;              // 0..15
  const int cS = (t & 15) * 8;
  {
#pragma unroll
    for (int p = 0; p < 4; ++p) {
      const int row = rS + p * 16;
      const int rg = m0 + row;
      const float* xp = &x[(size_t)(rg < NN ? rg : NN - 1) * F1 + cS];
      float4 lo = *(const float4*)xp;
      float4 hi = *(const float4*)(xp + 4);
      h2 q0 = h2{(_Float16)lo.x, (_Float16)lo.y};
      h2 q1 = h2{(_Float16)lo.z, (_Float16)lo.w};
      h2 q2 = h2{(_Float16)hi.x, (_Float16)hi.y};
      h2 q3 = h2{(_Float16)hi.z, (_Float16)hi.w};
      uint4 st; st.x = h22u(q0); st.y = h22u(q1); st.z = h22u(q2); st.w = h22u(q3);
      *(uint4*)&Al[row * PADK + cS] = st;
    }
  }
  auto stageB = [&](int hp, unsigned short* buf) {
#pragma unroll
    for (int p = 0; p < 4; ++p) {
      const int row = rS + p * 16;
      *(uint4*)&buf[row * PADK + cS] =
          *(const uint4*)&wt[(size_t)(hp * 64 + row) * F1 + cS];
    }
  };
  stageB(0, Bl0);
  __syncthreads();
  const int wave = t >> 6, lane = t & 63;
  const int mw = (wave >> 1) * 32, nw = (wave & 1) * 32;
  const int fr = lane & 15, fq = lane >> 4;
  for (int hp = 0; hp < 8; ++hp) {
    unsigned short* cur = (hp & 1) ? Bl1 : Bl0;
    unsigned short* nxt = (hp & 1) ? Bl0 : Bl1;
    if (hp < 7) stageB(hp + 1, nxt);   // overlaps with compute below
    f32x4 acc[2][2] = {};
#pragma unroll
    for (int ks = 0; ks < 4; ++ks) {
      const int ko = ks * 32 + fq * 8;
      f16x8 a[2], b[2];
#pragma unroll
      for (int i = 0; i < 2; ++i)
        a[i] = *(const f16x8*)&Al[(mw + i * 16 + fr) * PADK + ko];
#pragma unroll
      for (int j = 0; j < 2; ++j)
        b[j] = *(const f16x8*)&cur[(nw + j * 16 + fr) * PADK + ko];
      // operand swap: D = b (A-op, rows = wt cols) x a (B-op, cols = nodes)
#pragma unroll
      for (int i = 0; i < 2; ++i)
#pragma unroll
        for (int j = 0; j < 2; ++j)
          acc[i][j] = __builtin_amdgcn_mfma_f32_16x16x32_f16(b[j], a[i], acc[i][j], 0, 0, 0);
    }
    unsigned short* outp = (hp < 4) ? xlh : xrh;
    const int cbase = (hp * 64) & 255;
#pragma unroll
    for (int j = 0; j < 2; ++j) {
      const int col0 = cbase + nw + j * 16 + fq * 4;       // 4 consecutive cols
      const int head = col0 >> 5, f = col0 & 31;           // 4-aligned within head
      unsigned short* hp2 = outp + (size_t)head * NN * 32 + f;
#pragma unroll
      for (int i = 0; i < 2; ++i) {
        const int gm = m0 + mw + i * 16 + fr;              // one node per lane
        if (gm < NN) {
          h2 lo = h2{(_Float16)acc[i][j][0], (_Float16)acc[i][j][1]};
          h2 hi = h2{(_Float16)acc[i][j][2], (_Float16)acc[i][j][3]};
          uint2 st; st.x = h22u(lo); st.y = h22u(hi);
          *(uint2*)&hp2[(size_t)gm * 32] = st;             // 8B aligned store
        }
      }
    }
    __syncthreads();   // cur reads done before stage(hp+2) overwrites; nxt ready
  }
}

// ---------------- CSR scan ----------------
__global__ __launch_bounds__(256) void k_scan_part(const int* __restrict__ deg,
                                                   int* __restrict__ part) {
  int i = blockIdx.x * 256 + threadIdx.x;
  int v = (i < NN) ? deg[i] : 0;
  v += __shfl_xor(v, 1);  v += __shfl_xor(v, 2);  v += __shfl_xor(v, 4);
  v += __shfl_xor(v, 8);  v += __shfl_xor(v, 16); v += __shfl_xor(v, 32);
  __shared__ int w[4];
  if ((threadIdx.x & 63) == 0) w[threadIdx.x >> 6] = v;
  __syncthreads();
  if (threadIdx.x == 0) part[blockIdx.x] = w[0] + w[1] + w[2] + w[3];
}

// Block-local scan + inline prefix over part[0..b).
// Emits: offs[] (kept for layout stability), cursor deg[i]=beg+1 (slot 0 =
// self-loop, pre-placed csr[beg]=i, coalesced since excl is monotone in i),
// and NATURAL-ORDER packed metadata ninfo[i] = {beg, i|deg<<16} so both
// aggregation prologues are ONE load level.
__global__ __launch_bounds__(256) void k_scan_apply(int* __restrict__ deg,
                                                    const int* __restrict__ part,
                                                    int* __restrict__ offs,
                                                    uint2* __restrict__ ninfo,
                                                    unsigned short* __restrict__ csr) {
  __shared__ int lds[256];
  __shared__ int red[4];
  const int b = blockIdx.x, t = threadIdx.x;
  const int i = b * 256 + t;
  int v = (i < NN) ? deg[i] : 0;
  lds[t] = v;
  // prefix of preceding blocks' partial sums
  int pp = 0;
  for (int j = t; j < b; j += 256) pp += part[j];
  pp += __shfl_xor(pp, 1);  pp += __shfl_xor(pp, 2);  pp += __shfl_xor(pp, 4);
  pp += __shfl_xor(pp, 8);  pp += __shfl_xor(pp, 16); pp += __shfl_xor(pp, 32);
  if ((t & 63) == 0) red[t >> 6] = pp;
  __syncthreads();
  const int prefix = red[0] + red[1] + red[2] + red[3];
  for (int off = 1; off < 256; off <<= 1) {
    int u = (t >= off) ? lds[t - off] : 0;
    __syncthreads();
    lds[t] += u;
    __syncthreads();
  }
  int excl = prefix + lds[t] - v;
  if (i < NN) {
    offs[i] = excl;
    deg[i] = excl + 1;                  // cursor: slot 0 is the self-loop
    csr[excl] = (unsigned short)i;      // self-loop pre-placed
    ninfo[i] = make_uint2((unsigned)excl, (unsigned)i | ((unsigned)v << 16));
  }
  if (b == NB - 1 && t == 255) offs[NN] = prefix + lds[255];
}

// Real edges only (self-loops pre-placed by scan_apply).
__global__ void k_scatter(const int* __restrict__ ei, int* __restrict__ cur,
                          unsigned short* __restrict__ csr) {
  int e = blockIdx.x * 256 + threadIdx.x;
  if (e >= E0) return;
  int s = ei[e], d = ei[E0 + e];
  int pos = atomicAdd(&cur[d], 1);
  csr[pos] = (unsigned short)s;   // node ids < 65536
}

// ---------------- Layer-1 aggregation (head-pinned, 16 nodes/wave) ----------------
// head = blockIdx&7 pins each head's 3.2 MB slice to one XCD L2 (FETCH ~58 MB
// = compulsory). One wave = 16 nodes x 1 head; each 4-lane group owns one
// node's edge loop; p group-uniform -> no epilogue reduction.
// Prologue: ONE ninfo load gives {beg, deg}. Pipeline: csr ids lane-split
// two quads ahead; ids broadcast via DPP quad_perm; XL gathers one quad
// ahead. Tail via cndmask masking (p=0).
__global__ __launch_bounds__(256) void k_agg1(
    const unsigned short* __restrict__ xlh, const unsigned short* __restrict__ xrh,
    unsigned short* __restrict__ hb,
    const uint2* __restrict__ ninfo, const unsigned short* __restrict__ csr,
    const float* __restrict__ att, const float* __restrict__ b1) {
  const int b = blockIdx.x;
  const int head = b & 7;
  const int wave = threadIdx.x >> 6;
  const int lane = threadIdx.x & 63;
  const int g = lane >> 2;          // node group 0..15
  const int j4 = lane & 3;          // lane within group
  const int idxn = (b >> 3) * 64 + wave * 16 + g;
  const bool valid = idxn < NN;
  const int n = valid ? idxn : 0;
  const int colh = j4 * 8;          // feat offset within head
  const int col = head * 32 + colh; // global feat col (att/b1)
  const unsigned short* xlhead = xlh + (size_t)head * NN * 32;

  const uint2 nf = ninfo[n];
  const int beg = (int)nf.x;
  const int fin = valid ? beg + (int)(nf.y >> 16) : beg;

  const uint4 xru = *(const uint4*)&xrh[((size_t)head * NN + n) * 32 + colh];
  h2 xr2[4];
  xr2[0] = u2h2(xru.x); xr2[1] = u2h2(xru.y);
  xr2[2] = u2h2(xru.z); xr2[3] = u2h2(xru.w);
  float at8[8];
  *(float4*)&at8[0] = *(const float4*)&att[col];
  *(float4*)&at8[4] = *(const float4*)&att[col + 4];
  h2 ath6[4], ath4[4];
#pragma unroll
  for (int j = 0; j < 4; ++j) {
    ath6[j] = h2{(_Float16)(at8[2 * j] * (0.6f * LOG2E)),
                 (_Float16)(at8[2 * j + 1] * (0.6f * LOG2E))};
    ath4[j] = h2{(_Float16)(at8[2 * j] * (0.4f * LOG2E)),
                 (_Float16)(at8[2 * j + 1] * (0.4f * LOG2E))};
  }
  float l = 0.f;
  h2 acc2[4] = {h2{0, 0}, h2{0, 0}, h2{0, 0}, h2{0, 0}};

  // lane-split id load: lane j4 fetches csr[base+j4], clamped into [beg,fin)
  auto ldids = [&](int base) -> int {
    int a = base + j4;
    a = (a < fin) ? a : beg;      // empty groups read csr[beg] (self-loop)
    return (int)csr[a];
  };
  auto XLrow = [&](int s) -> uint4 {
    return *(const uint4*)&xlhead[(size_t)s * 32 + colh];
  };
  auto edge = [&](const uint4& w, bool live) {
    h2 xh[4];
    xh[0] = u2h2(w.x); xh[1] = u2h2(w.y); xh[2] = u2h2(w.z); xh[3] = u2h2(w.w);
    float cv = 0.f, ca = 0.f;
#pragma unroll
    for (int j = 0; j < 4; ++j) {
      h2 v = xh[j] + xr2[j];
      h2 a = u2h2(h22u(v) & 0x7FFF7FFFu);       // |v| per half
      cv = __builtin_amdgcn_fdot2(v, ath6[j], cv, false);
      ca = __builtin_amdgcn_fdot2(a, ath4[j], ca, false);
    }
    float c = cv + ca;
    c = dpp_add<0xB1>(c);             // + lane^1 (quad_perm, no DS op)
    c = dpp_add<0x4E>(c);             // + lane^2 -> group total in all 4 lanes
    float p = exp2f(c);
    p = live ? p : 0.f;
    l += p;
    const _Float16 ph = (_Float16)p;
    const h2 p2 = h2{ph, ph};
#pragma unroll
    for (int j = 0; j < 4; ++j) acc2[j] += p2 * xh[j];
  };

  // software pipeline: w = quad idx, ids1 = ids for quad idx+4
  int ids = ldids(beg);
  uint4 w0 = XLrow(dpp_bcast<0>(ids));
  uint4 w1 = XLrow(dpp_bcast<1>(ids));
  uint4 w2 = XLrow(dpp_bcast<2>(ids));
  uint4 w3 = XLrow(dpp_bcast<3>(ids));
  int ids1 = ldids(beg + 4);
  for (int idx = beg; idx < fin; idx += 4) {
    const uint4 v0 = XLrow(dpp_bcast<0>(ids1));   // gathers for quad idx+4
    const uint4 v1 = XLrow(dpp_bcast<1>(ids1));
    const uint4 v2 = XLrow(dpp_bcast<2>(ids1));
    const uint4 v3 = XLrow(dpp_bcast<3>(ids1));
    const int ids2 = ldids(idx + 8);              // ids for quad idx+8
    edge(w0, true);                               // idx < fin by loop cond
    edge(w1, idx + 1 < fin);
    edge(w2, idx + 2 < fin);
    edge(w3, idx + 3 < fin);
    w0 = v0; w1 = v1; w2 = v2; w3 = v3; ids1 = ids2;
  }

  if (valid) {
    const float rl = __builtin_amdgcn_rcpf(l + 1e-16f);
    float b8[8], o[8];
    *(float4*)&b8[0] = *(const float4*)&b1[col];
    *(float4*)&b8[4] = *(const float4*)&b1[col + 4];
#pragma unroll
    for (int j = 0; j < 4; ++j) {
      o[2 * j]     = (float)acc2[j][0] * rl + b8[2 * j];
      o[2 * j + 1] = (float)acc2[j][1] * rl + b8[2 * j + 1];
    }
#pragma unroll
    for (int k = 0; k < 8; ++k)
      o[k] = o[k] > 0.f ? o[k] : exp2f(o[k] * LOG2E) - 1.f;  // cheap ELU
    ushort4 p;
    p.x = f2h(o[0]); p.y = f2h(o[1]); p.z = f2h(o[2]); p.w = f2h(o[3]);
    ushort4 q;
    q.x = f2h(o[4]); q.y = f2h(o[5]); q.z = f2h(o[6]); q.w = f2h(o[7]);
    uint4 packed;
    packed.x = *(unsigned*)&p.x; packed.y = *(unsigned*)&p.z;
    packed.z = *(unsigned*)&q.x; packed.w = *(unsigned*)&q.z;
    *(uint4*)&hb[(size_t)n * D1 + col] = packed;
  }
}

// ---------------- Layer-2 GEMM via MFMA (fp16, no LDS) ----------------
// h2[50000, 32] = hb @ Wt2^T. B fragments direct from global (wt2 is 16 KB,
// L1-resident). No barrier.
__global__ __launch_bounds__(256) void k_gemm2m(
    const unsigned short* __restrict__ hb, const unsigned short* __restrict__ wt2,
    unsigned short* __restrict__ h2lh, float* __restrict__ h2r) {
  const int t = threadIdx.x;
  const int wave = t >> 6, lane = t & 63;
  const int fr = lane & 15, fq = lane >> 4;
  const int m0 = blockIdx.x * 128 + wave * 32;
  f32x4 acc[2][2] = {};
#pragma unroll
  for (int ks = 0; ks < 8; ++ks) {
    const int ko = ks * 32 + fq * 8;
    f16x8 a[2], b[2];
#pragma unroll
    for (int i = 0; i < 2; ++i) {
      int row = m0 + i * 16 + fr; if (row >= NN) row = NN - 1;
      a[i] = *(const f16x8*)&hb[(size_t)row * D1 + ko];
    }
#pragma unroll
    for (int j = 0; j < 2; ++j)
      b[j] = *(const f16x8*)&wt2[(j * 16 + fr) * 256 + ko];
#pragma unroll
    for (int i = 0; i < 2; ++i)
#pragma unroll
      for (int j = 0; j < 2; ++j)
        acc[i][j] = __builtin_amdgcn_mfma_f32_16x16x32_f16(a[i], b[j], acc[i][j], 0, 0, 0);
  }
#pragma unroll
  for (int i = 0; i < 2; ++i) {
    const int gm0 = m0 + i * 16 + fq * 4;
#pragma unroll
    for (int r = 0; r < 4; ++r) {
      const int gm = gm0 + r;
      if (gm < NN) {
        h2lh[(size_t)gm * C2 + fr] = f2h(acc[i][0][r]);
        h2r[(size_t)gm * C2 + fr] = acc[i][1][r];
      }
    }
  }
}

// ---------------- Layer-2 aggregation ----------------
// Unrolled 2-wide (8 edges/wave-iter); prologue via ONE ninfo load.
__global__ __launch_bounds__(256) void k_agg2(
    const unsigned short* __restrict__ h2lh, const float* __restrict__ h2r,
    const uint2* __restrict__ ninfo, const unsigned short* __restrict__ csr,
    const float* __restrict__ att2, const float* __restrict__ b2,
    float* __restrict__ out) {
  const int wave = threadIdx.x >> 6;
  const int lane = threadIdx.x & 63;
  const int n = blockIdx.x * 4 + wave;
  if (n >= NN) return;
  const int c = lane & 15, g = lane >> 4;
  const float xr_v = h2r[(size_t)n * C2 + c];
  const float att_v = att2[c] * LOG2E;
  float l = 0.f, acc = 0.f;
  const uint2 nf = ninfo[n];
  const int beg = (int)nf.x;
  const int fin = beg + (int)(nf.y >> 16);
  for (int idx = beg + g; idx < fin; idx += 8) {
    const int i1 = idx + 4;
    const bool m1 = i1 < fin;
    const int s0 = csr[idx];
    const int s1 = csr[m1 ? i1 : idx];
    const float xl0 = h2f(h2lh[(size_t)s0 * C2 + c]);
    const float xl1 = h2f(h2lh[(size_t)s1 * C2 + c]);
    float v0 = xl0 + xr_v; v0 = fmaxf(v0, 0.2f * v0);
    float v1 = xl1 + xr_v; v1 = fmaxf(v1, 0.2f * v1);
    float sc0 = v0 * att_v, sc1 = v1 * att_v;
    sc0 = dpp_add<0xB1>(sc0);   sc1 = dpp_add<0xB1>(sc1);
    sc0 = dpp_add<0x4E>(sc0);   sc1 = dpp_add<0x4E>(sc1);
    sc0 = dpp_add<0x124>(sc0);  sc1 = dpp_add<0x124>(sc1);
    sc0 = dpp_add<0x128>(sc0);  sc1 = dpp_add<0x128>(sc1);
    const float p0 = exp2f(sc0);
    const float p1 = m1 ? exp2f(sc1) : 0.f;
    l += p0 + p1;
    acc = fmaf(p0, xl0, fmaf(p1, xl1, acc));
  }
  l += __shfl_xor(l, 16);   l += __shfl_xor(l, 32);
  acc += __shfl_xor(acc, 16); acc += __shfl_xor(acc, 32);
  float o = acc * __builtin_amdgcn_rcpf(l + 1e-16f) + b2[c];
  o = o > 0.f ? o : 0.01f * o;
  if (lane < 16) out[(size_t)n * C2 + c] = o;
}

extern "C" void kernel_launch(void* const* d_in, const int* in_sizes, int n_in,
                              void* d_out, int out_size, void* d_ws, size_t ws_size,
                              hipStream_t stream) {
  const float* x    = (const float*)d_in[0];
  const int*   ei   = (const int*)d_in[1];
  const float* W1l  = (const float*)d_in[2];
  const float* W1r  = (const float*)d_in[3];
  const float* att1 = (const float*)d_in[4];
  const float* b1   = (const float*)d_in[5];
  const float* W2l  = (const float*)d_in[6];
  const float* W2r  = (const float*)d_in[7];
  const float* att2 = (const float*)d_in[8];
  const float* b2   = (const float*)d_in[9];
  float* out = (float*)d_out;

  // Workspace layout (~79.3 MB):
  unsigned short* xlh = (unsigned short*)d_ws;        // [8][NN][32] fp16
  unsigned short* xrh = xlh + (size_t)NN * D1;        // [8][NN][32] fp16
  unsigned short* hb  = xrh + (size_t)NN * D1;        // [NN][256] fp16
  int* deg  = (int*)(hb + (size_t)NN * D1);           // NN (becomes cursor)
  int* part = deg + NN;                               // NB
  int* offs = part + NB;                              // NN+1 (+1 pad for align)
  uint2* ninfo = (uint2*)(offs + NN + 2);             // NN {beg, n|deg<<16}
  unsigned short* csr = (unsigned short*)(ninfo + NN);  // ET u16
  unsigned short* wt  = csr + ET + 2;                 // 512*128 fp16
  unsigned short* wt2 = wt + 512 * F1;                // 32*256 fp16
  unsigned short* h2lh = xlh;                         // alias: xlh dead after agg1
  float* h2r = (float*)(h2lh + (size_t)NN * C2);

  hipMemsetAsync(deg, 0, NN * sizeof(int), stream);
  k_prep<<<288 + (ET + 255) / 256, 256, 0, stream>>>(
      W1l, W1r, W2l, W2r, ei, wt, wt2, deg);
  k_gemm1m<<<MPAD / 64, 256, 0, stream>>>(x, wt, xlh, xrh);
  k_scan_part<<<NB, 256, 0, stream>>>(deg, part);
  k_scan_apply<<<NB, 256, 0, stream>>>(deg, part, offs, ninfo, csr);
  k_scatter<<<(E0 + 255) / 256, 256, 0, stream>>>(ei, deg, csr);
  k_agg1<<<NBK1 * 8, 256, 0, stream>>>(xlh, xrh, hb, ninfo, csr, att1, b1);
  k_gemm2m<<<(NN + 127) / 128, 256, 0, stream>>>(hb, wt2, h2lh, h2r);
  k_agg2<<<NN / 4, 256, 0, stream>>>(h2lh, h2r, ninfo, csr, att2, b2, out);
}

// Round 13
// 253.402 us; speedup vs baseline: 1.0819x; 1.0111x over previous
//
#include <hip/hip_runtime.h>
#include <math.h>

#define NN 50000
#define E0 640000
#define ET 690000   // E0 + NN self loops
#define F1 128
#define D1 256      // 8 heads * 32
#define C2 16
#define NB 196      // ceil(NN/256)
#define MPAD 50048  // 391*128, padded node count for MFMA tiles
#define PADK 136    // 128 + 8 pad (breaks ds_read_b128 bank conflicts)
#define LOG2E 1.4426950408889634f
#define NBK1 782    // ceil(NN/64) node-blocks for agg1

typedef _Float16 f16x8 __attribute__((ext_vector_type(8)));
typedef _Float16 h2 __attribute__((ext_vector_type(2)));
typedef __attribute__((ext_vector_type(4))) float f32x4;

__device__ __forceinline__ unsigned short f2h(float f) {
  union { _Float16 h; unsigned short u; } c;
  c.h = (_Float16)f;
  return c.u;
}
__device__ __forceinline__ float h2f(unsigned short u) {
  union { unsigned short u; _Float16 h; } c; c.u = u; return (float)c.h;
}
__device__ __forceinline__ h2 u2h2(unsigned u) {
  union { unsigned u; h2 h; } c; c.u = u; return c.h;
}
__device__ __forceinline__ unsigned h22u(h2 h) {
  union { h2 h; unsigned u; } c; c.h = h; return c.u;
}

// DPP-based lane-group sums: v_add_f32 with DPP modifier, no DS ops.
// 0xB1 = quad_perm [1,0,3,2] (xor 1), 0x4E = quad_perm [2,3,0,1] (xor 2).
template <int CTRL>
__device__ __forceinline__ float dpp_add(float c) {
  int t = __builtin_amdgcn_update_dpp(0, __builtin_bit_cast(int, c), CTRL, 0xF, 0xF, true);
  return c + __builtin_bit_cast(float, t);
}
// Broadcast lane K of each quad to all 4 lanes of the quad (quad_perm K,K,K,K).
template <int K>
__device__ __forceinline__ int dpp_bcast(int v) {
  constexpr int ctrl = K | (K << 2) | (K << 4) | (K << 6);
  return __builtin_amdgcn_update_dpp(0, v, ctrl, 0xF, 0xF, true);
}

// ---------------- prep: weight converts + degree histogram ----------------
// blocks [0,256): wt | [256,288): wt2 | rest: edge histogram.
__global__ __launch_bounds__(256) void k_prep(
    const float* __restrict__ Wl, const float* __restrict__ Wr,
    const float* __restrict__ W2l, const float* __restrict__ W2r,
    const int* __restrict__ ei,
    unsigned short* __restrict__ wt, unsigned short* __restrict__ wt2,
    int* __restrict__ deg) {
  const int b = blockIdx.x;
  if (b < 256) {
    int tid = b * 256 + threadIdx.x;            // = n*128 + k
    int n = tid >> 7, k = tid & 127;
    float v = (n < 256) ? Wl[k * 256 + n] : Wr[k * 256 + (n - 256)];
    wt[tid] = f2h(v);
  } else if (b < 288) {
    int tid = (b - 256) * 256 + threadIdx.x;    // = n*256 + k
    int n = tid >> 8, k = tid & 255;
    float v = (n < 16) ? W2l[k * 16 + n] : W2r[k * 16 + (n - 16)];
    wt2[tid] = f2h(v);
  } else {
    int e = (b - 288) * 256 + threadIdx.x;
    if (e >= ET) return;
    int d = (e < E0) ? ei[E0 + e] : (e - E0);
    atomicAdd(&deg[d], 1);
  }
}

// ---------------- Layer-1 GEMM via MFMA (fp16) ----------------
// R9-proven configuration (the 253.5us champion): A-tile (64 rows) staged
// ONCE per block; internal loop over the 4 n0 panels re-stages Bl only
// (load-bearing: R10 direct-B +20us, R12 half-panel dbuf +3us); operand-swap
// epilogue: D = Wt_frag . x_frag -> lane holds 4 consecutive wt-cols at one
// node (col=lane&15 -> node, row=(lane>>4)*4+reg -> wt col) -> one aligned
// 8B uint2 store per (i,j), killing write-combine amplification (R9: -9us).
// Outputs HEAD-MAJOR: out[head][node][32].
__global__ __launch_bounds__(256) void k_gemm1m(
    const float* __restrict__ x, const unsigned short* __restrict__ wt,
    unsigned short* __restrict__ xlh, unsigned short* __restrict__ xrh) {
  __shared__ unsigned short Al[64 * PADK];
  __shared__ unsigned short Bl[128 * PADK];
  const int t = threadIdx.x;
  const int m0 = blockIdx.x * 64;
  {
    const int r = t >> 4;             // 0..15
    const int c = (t & 15) * 8;
#pragma unroll
    for (int p = 0; p < 4; ++p) {
      const int row = r + p * 16;
      const int rg = m0 + row;
      const float* xp = &x[(size_t)(rg < NN ? rg : NN - 1) * F1 + c];
      float4 lo = *(const float4*)xp;
      float4 hi = *(const float4*)(xp + 4);
      h2 q0 = h2{(_Float16)lo.x, (_Float16)lo.y};
      h2 q1 = h2{(_Float16)lo.z, (_Float16)lo.w};
      h2 q2 = h2{(_Float16)hi.x, (_Float16)hi.y};
      h2 q3 = h2{(_Float16)hi.z, (_Float16)hi.w};
      uint4 st; st.x = h22u(q0); st.y = h22u(q1); st.z = h22u(q2); st.w = h22u(q3);
      *(uint4*)&Al[row * PADK + c] = st;
    }
  }
  const int wave = t >> 6, lane = t & 63;
  const int mw = (wave >> 1) * 32, nw = (wave & 1) * 64;
  const int fr = lane & 15, fq = lane >> 4;
  for (int ny = 0; ny < 4; ++ny) {
    const int n0 = ny * 128;
    {
      const int r = t >> 4;
      const int c = (t & 15) * 8;
#pragma unroll
      for (int p = 0; p < 8; ++p) {
        const int row = r + p * 16;
        *(float4*)&Bl[row * PADK + c] = *(const float4*)&wt[(size_t)(n0 + row) * F1 + c];
      }
    }
    __syncthreads();
    f32x4 acc[2][4] = {};
#pragma unroll
    for (int ks = 0; ks < 4; ++ks) {
      const int ko = ks * 32 + fq * 8;
      f16x8 a[2], b[4];
#pragma unroll
      for (int i = 0; i < 2; ++i)
        a[i] = *(const f16x8*)&Al[(mw + i * 16 + fr) * PADK + ko];
#pragma unroll
      for (int j = 0; j < 4; ++j)
        b[j] = *(const f16x8*)&Bl[(nw + j * 16 + fr) * PADK + ko];
      // operand swap: D = b (A-op, rows = wt cols) x a (B-op, cols = nodes)
#pragma unroll
      for (int i = 0; i < 2; ++i)
#pragma unroll
        for (int j = 0; j < 4; ++j)
          acc[i][j] = __builtin_amdgcn_mfma_f32_16x16x32_f16(b[j], a[i], acc[i][j], 0, 0, 0);
    }
    __syncthreads();   // all waves done reading Bl before next restage
    unsigned short* outp = (n0 < 256) ? xlh : xrh;
#pragma unroll
    for (int j = 0; j < 4; ++j) {
      const int col0 = (n0 & 255) + nw + j * 16 + fq * 4;  // 4 consecutive cols
      const int head = col0 >> 5, f = col0 & 31;           // 4-aligned within head
      unsigned short* hp = outp + (size_t)head * NN * 32 + f;
#pragma unroll
      for (int i = 0; i < 2; ++i) {
        const int gm = m0 + mw + i * 16 + fr;              // one node per lane
        if (gm < NN) {
          h2 lo = h2{(_Float16)acc[i][j][0], (_Float16)acc[i][j][1]};
          h2 hi = h2{(_Float16)acc[i][j][2], (_Float16)acc[i][j][3]};
          uint2 st; st.x = h22u(lo); st.y = h22u(hi);
          *(uint2*)&hp[(size_t)gm * 32] = st;              // 8B aligned store
        }
      }
    }
  }
}

// ---------------- CSR scan ----------------
__global__ __launch_bounds__(256) void k_scan_part(const int* __restrict__ deg,
                                                   int* __restrict__ part) {
  int i = blockIdx.x * 256 + threadIdx.x;
  int v = (i < NN) ? deg[i] : 0;
  v += __shfl_xor(v, 1);  v += __shfl_xor(v, 2);  v += __shfl_xor(v, 4);
  v += __shfl_xor(v, 8);  v += __shfl_xor(v, 16); v += __shfl_xor(v, 32);
  __shared__ int w[4];
  if ((threadIdx.x & 63) == 0) w[threadIdx.x >> 6] = v;
  __syncthreads();
  if (threadIdx.x == 0) part[blockIdx.x] = w[0] + w[1] + w[2] + w[3];
}

// Block-local scan + inline prefix over part[0..b).
// Emits: offs[] (kept for layout stability), cursor deg[i]=beg+1 (slot 0 =
// self-loop, pre-placed csr[beg]=i, coalesced since excl is monotone in i),
// and NATURAL-ORDER packed metadata ninfo[i] = {beg, i|deg<<16} so both
// aggregation prologues are ONE load level.
__global__ __launch_bounds__(256) void k_scan_apply(int* __restrict__ deg,
                                                    const int* __restrict__ part,
                                                    int* __restrict__ offs,
                                                    uint2* __restrict__ ninfo,
                                                    unsigned short* __restrict__ csr) {
  __shared__ int lds[256];
  __shared__ int red[4];
  const int b = blockIdx.x, t = threadIdx.x;
  const int i = b * 256 + t;
  int v = (i < NN) ? deg[i] : 0;
  lds[t] = v;
  // prefix of preceding blocks' partial sums
  int pp = 0;
  for (int j = t; j < b; j += 256) pp += part[j];
  pp += __shfl_xor(pp, 1);  pp += __shfl_xor(pp, 2);  pp += __shfl_xor(pp, 4);
  pp += __shfl_xor(pp, 8);  pp += __shfl_xor(pp, 16); pp += __shfl_xor(pp, 32);
  if ((t & 63) == 0) red[t >> 6] = pp;
  __syncthreads();
  const int prefix = red[0] + red[1] + red[2] + red[3];
  for (int off = 1; off < 256; off <<= 1) {
    int u = (t >= off) ? lds[t - off] : 0;
    __syncthreads();
    lds[t] += u;
    __syncthreads();
  }
  int excl = prefix + lds[t] - v;
  if (i < NN) {
    offs[i] = excl;
    deg[i] = excl + 1;                  // cursor: slot 0 is the self-loop
    csr[excl] = (unsigned short)i;      // self-loop pre-placed
    ninfo[i] = make_uint2((unsigned)excl, (unsigned)i | ((unsigned)v << 16));
  }
  if (b == NB - 1 && t == 255) offs[NN] = prefix + lds[255];
}

// Real edges only (self-loops pre-placed by scan_apply).
__global__ void k_scatter(const int* __restrict__ ei, int* __restrict__ cur,
                          unsigned short* __restrict__ csr) {
  int e = blockIdx.x * 256 + threadIdx.x;
  if (e >= E0) return;
  int s = ei[e], d = ei[E0 + e];
  int pos = atomicAdd(&cur[d], 1);
  csr[pos] = (unsigned short)s;   // node ids < 65536
}

// ---------------- Layer-1 aggregation (head-pinned, 16 nodes/wave) ----------------
// head = blockIdx&7 pins each head's 3.2 MB slice to one XCD L2 (FETCH ~58 MB
// = compulsory). One wave = 16 nodes x 1 head; each 4-lane group owns one
// node's edge loop; p group-uniform -> no epilogue reduction.
// Prologue: ONE ninfo load gives {beg, deg}. Pipeline: csr ids lane-split
// two quads ahead; ids broadcast via DPP quad_perm; XL gathers one quad
// ahead. Tail via cndmask masking (p=0).
__global__ __launch_bounds__(256) void k_agg1(
    const unsigned short* __restrict__ xlh, const unsigned short* __restrict__ xrh,
    unsigned short* __restrict__ hb,
    const uint2* __restrict__ ninfo, const unsigned short* __restrict__ csr,
    const float* __restrict__ att, const float* __restrict__ b1) {
  const int b = blockIdx.x;
  const int head = b & 7;
  const int wave = threadIdx.x >> 6;
  const int lane = threadIdx.x & 63;
  const int g = lane >> 2;          // node group 0..15
  const int j4 = lane & 3;          // lane within group
  const int idxn = (b >> 3) * 64 + wave * 16 + g;
  const bool valid = idxn < NN;
  const int n = valid ? idxn : 0;
  const int colh = j4 * 8;          // feat offset within head
  const int col = head * 32 + colh; // global feat col (att/b1)
  const unsigned short* xlhead = xlh + (size_t)head * NN * 32;

  const uint2 nf = ninfo[n];
  const int beg = (int)nf.x;
  const int fin = valid ? beg + (int)(nf.y >> 16) : beg;

  const uint4 xru = *(const uint4*)&xrh[((size_t)head * NN + n) * 32 + colh];
  h2 xr2[4];
  xr2[0] = u2h2(xru.x); xr2[1] = u2h2(xru.y);
  xr2[2] = u2h2(xru.z); xr2[3] = u2h2(xru.w);
  float at8[8];
  *(float4*)&at8[0] = *(const float4*)&att[col];
  *(float4*)&at8[4] = *(const float4*)&att[col + 4];
  h2 ath6[4], ath4[4];
#pragma unroll
  for (int j = 0; j < 4; ++j) {
    ath6[j] = h2{(_Float16)(at8[2 * j] * (0.6f * LOG2E)),
                 (_Float16)(at8[2 * j + 1] * (0.6f * LOG2E))};
    ath4[j] = h2{(_Float16)(at8[2 * j] * (0.4f * LOG2E)),
                 (_Float16)(at8[2 * j + 1] * (0.4f * LOG2E))};
  }
  float l = 0.f;
  h2 acc2[4] = {h2{0, 0}, h2{0, 0}, h2{0, 0}, h2{0, 0}};

  // lane-split id load: lane j4 fetches csr[base+j4], clamped into [beg,fin)
  auto ldids = [&](int base) -> int {
    int a = base + j4;
    a = (a < fin) ? a : beg;      // empty groups read csr[beg] (self-loop)
    return (int)csr[a];
  };
  auto XLrow = [&](int s) -> uint4 {
    return *(const uint4*)&xlhead[(size_t)s * 32 + colh];
  };
  auto edge = [&](const uint4& w, bool live) {
    h2 xh[4];
    xh[0] = u2h2(w.x); xh[1] = u2h2(w.y); xh[2] = u2h2(w.z); xh[3] = u2h2(w.w);
    float cv = 0.f, ca = 0.f;
#pragma unroll
    for (int j = 0; j < 4; ++j) {
      h2 v = xh[j] + xr2[j];
      h2 a = u2h2(h22u(v) & 0x7FFF7FFFu);       // |v| per half
      cv = __builtin_amdgcn_fdot2(v, ath6[j], cv, false);
      ca = __builtin_amdgcn_fdot2(a, ath4[j], ca, false);
    }
    float c = cv + ca;
    c = dpp_add<0xB1>(c);             // + lane^1 (quad_perm, no DS op)
    c = dpp_add<0x4E>(c);             // + lane^2 -> group total in all 4 lanes
    float p = exp2f(c);
    p = live ? p : 0.f;
    l += p;
    const _Float16 ph = (_Float16)p;
    const h2 p2 = h2{ph, ph};
#pragma unroll
    for (int j = 0; j < 4; ++j) acc2[j] += p2 * xh[j];
  };

  // software pipeline: w = quad idx, ids1 = ids for quad idx+4
  int ids = ldids(beg);
  uint4 w0 = XLrow(dpp_bcast<0>(ids));
  uint4 w1 = XLrow(dpp_bcast<1>(ids));
  uint4 w2 = XLrow(dpp_bcast<2>(ids));
  uint4 w3 = XLrow(dpp_bcast<3>(ids));
  int ids1 = ldids(beg + 4);
  for (int idx = beg; idx < fin; idx += 4) {
    const uint4 v0 = XLrow(dpp_bcast<0>(ids1));   // gathers for quad idx+4
    const uint4 v1 = XLrow(dpp_bcast<1>(ids1));
    const uint4 v2 = XLrow(dpp_bcast<2>(ids1));
    const uint4 v3 = XLrow(dpp_bcast<3>(ids1));
    const int ids2 = ldids(idx + 8);              // ids for quad idx+8
    edge(w0, true);                               // idx < fin by loop cond
    edge(w1, idx + 1 < fin);
    edge(w2, idx + 2 < fin);
    edge(w3, idx + 3 < fin);
    w0 = v0; w1 = v1; w2 = v2; w3 = v3; ids1 = ids2;
  }

  if (valid) {
    const float rl = __builtin_amdgcn_rcpf(l + 1e-16f);
    float b8[8], o[8];
    *(float4*)&b8[0] = *(const float4*)&b1[col];
    *(float4*)&b8[4] = *(const float4*)&b1[col + 4];
#pragma unroll
    for (int j = 0; j < 4; ++j) {
      o[2 * j]     = (float)acc2[j][0] * rl + b8[2 * j];
      o[2 * j + 1] = (float)acc2[j][1] * rl + b8[2 * j + 1];
    }
#pragma unroll
    for (int k = 0; k < 8; ++k)
      o[k] = o[k] > 0.f ? o[k] : exp2f(o[k] * LOG2E) - 1.f;  // cheap ELU
    ushort4 p;
    p.x = f2h(o[0]); p.y = f2h(o[1]); p.z = f2h(o[2]); p.w = f2h(o[3]);
    ushort4 q;
    q.x = f2h(o[4]); q.y = f2h(o[5]); q.z = f2h(o[6]); q.w = f2h(o[7]);
    uint4 packed;
    packed.x = *(unsigned*)&p.x; packed.y = *(unsigned*)&p.z;
    packed.z = *(unsigned*)&q.x; packed.w = *(unsigned*)&q.z;
    *(uint4*)&hb[(size_t)n * D1 + col] = packed;
  }
}

// ---------------- Layer-2 GEMM via MFMA (fp16, no LDS) ----------------
// h2[50000, 32] = hb @ Wt2^T. B fragments direct from global (wt2 is 16 KB,
// L1-resident). No barrier.
__global__ __launch_bounds__(256) void k_gemm2m(
    const unsigned short* __restrict__ hb, const unsigned short* __restrict__ wt2,
    unsigned short* __restrict__ h2lh, float* __restrict__ h2r) {
  const int t = threadIdx.x;
  const int wave = t >> 6, lane = t & 63;
  const int fr = lane & 15, fq = lane >> 4;
  const int m0 = blockIdx.x * 128 + wave * 32;
  f32x4 acc[2][2] = {};
#pragma unroll
  for (int ks = 0; ks < 8; ++ks) {
    const int ko = ks * 32 + fq * 8;
    f16x8 a[2], b[2];
#pragma unroll
    for (int i = 0; i < 2; ++i) {
      int row = m0 + i * 16 + fr; if (row >= NN) row = NN - 1;
      a[i] = *(const f16x8*)&hb[(size_t)row * D1 + ko];
    }
#pragma unroll
    for (int j = 0; j < 2; ++j)
      b[j] = *(const f16x8*)&wt2[(j * 16 + fr) * 256 + ko];
#pragma unroll
    for (int i = 0; i < 2; ++i)
#pragma unroll
      for (int j = 0; j < 2; ++j)
        acc[i][j] = __builtin_amdgcn_mfma_f32_16x16x32_f16(a[i], b[j], acc[i][j], 0, 0, 0);
  }
#pragma unroll
  for (int i = 0; i < 2; ++i) {
    const int gm0 = m0 + i * 16 + fq * 4;
#pragma unroll
    for (int r = 0; r < 4; ++r) {
      const int gm = gm0 + r;
      if (gm < NN) {
        h2lh[(size_t)gm * C2 + fr] = f2h(acc[i][0][r]);
        h2r[(size_t)gm * C2 + fr] = acc[i][1][r];
      }
    }
  }
}

// ---------------- Layer-2 aggregation ----------------
// R13: unrolled 4-wide (16 edge-slots/wave-iter, stride 16): mean deg 13.8
// -> most waves finish the loop in ONE iteration with all 4 gathers and 4
// independent DPP-reduce chains in flight. agg2 has only ~12.5K waves
// (weakest TLP in the pipeline), so shortening the serial chain per wave
// is the lever here. Prologue via ONE ninfo load.
__global__ __launch_bounds__(256) void k_agg2(
    const unsigned short* __restrict__ h2lh, const float* __restrict__ h2r,
    const uint2* __restrict__ ninfo, const unsigned short* __restrict__ csr,
    const float* __restrict__ att2, const float* __restrict__ b2,
    float* __restrict__ out) {
  const int wave = threadIdx.x >> 6;
  const int lane = threadIdx.x & 63;
  const int n = blockIdx.x * 4 + wave;
  if (n >= NN) return;
  const int c = lane & 15, g = lane >> 4;
  const float xr_v = h2r[(size_t)n * C2 + c];
  const float att_v = att2[c] * LOG2E;
  float l = 0.f, acc = 0.f;
  const uint2 nf = ninfo[n];
  const int beg = (int)nf.x;
  const int fin = beg + (int)(nf.y >> 16);
  for (int idx = beg + g; idx < fin; idx += 16) {
    const int i1 = idx + 4, i2 = idx + 8, i3 = idx + 12;
    const bool m1 = i1 < fin, m2 = i2 < fin, m3 = i3 < fin;
    const int s0 = csr[idx];
    const int s1 = csr[m1 ? i1 : idx];
    const int s2 = csr[m2 ? i2 : idx];
    const int s3 = csr[m3 ? i3 : idx];
    const float xl0 = h2f(h2lh[(size_t)s0 * C2 + c]);
    const float xl1 = h2f(h2lh[(size_t)s1 * C2 + c]);
    const float xl2 = h2f(h2lh[(size_t)s2 * C2 + c]);
    const float xl3 = h2f(h2lh[(size_t)s3 * C2 + c]);
    float v0 = xl0 + xr_v; v0 = fmaxf(v0, 0.2f * v0);
    float v1 = xl1 + xr_v; v1 = fmaxf(v1, 0.2f * v1);
    float v2 = xl2 + xr_v; v2 = fmaxf(v2, 0.2f * v2);
    float v3 = xl3 + xr_v; v3 = fmaxf(v3, 0.2f * v3);
    float sc0 = v0 * att_v, sc1 = v1 * att_v, sc2 = v2 * att_v, sc3 = v3 * att_v;
    sc0 = dpp_add<0xB1>(sc0);   sc1 = dpp_add<0xB1>(sc1);
    sc2 = dpp_add<0xB1>(sc2);   sc3 = dpp_add<0xB1>(sc3);
    sc0 = dpp_add<0x4E>(sc0);   sc1 = dpp_add<0x4E>(sc1);
    sc2 = dpp_add<0x4E>(sc2);   sc3 = dpp_add<0x4E>(sc3);
    sc0 = dpp_add<0x124>(sc0);  sc1 = dpp_add<0x124>(sc1);
    sc2 = dpp_add<0x124>(sc2);  sc3 = dpp_add<0x124>(sc3);
    sc0 = dpp_add<0x128>(sc0);  sc1 = dpp_add<0x128>(sc1);
    sc2 = dpp_add<0x128>(sc2);  sc3 = dpp_add<0x128>(sc3);
    const float p0 = exp2f(sc0);
    const float p1 = m1 ? exp2f(sc1) : 0.f;
    const float p2 = m2 ? exp2f(sc2) : 0.f;
    const float p3 = m3 ? exp2f(sc3) : 0.f;
    l += (p0 + p1) + (p2 + p3);
    acc = fmaf(p0, xl0, fmaf(p1, xl1, fmaf(p2, xl2, fmaf(p3, xl3, acc))));
  }
  l += __shfl_xor(l, 16);   l += __shfl_xor(l, 32);
  acc += __shfl_xor(acc, 16); acc += __shfl_xor(acc, 32);
  float o = acc * __builtin_amdgcn_rcpf(l + 1e-16f) + b2[c];
  o = o > 0.f ? o : 0.01f * o;
  if (lane < 16) out[(size_t)n * C2 + c] = o;
}

extern "C" void kernel_launch(void* const* d_in, const int* in_sizes, int n_in,
                              void* d_out, int out_size, void* d_ws, size_t ws_size,
                              hipStream_t stream) {
  const float* x    = (const float*)d_in[0];
  const int*   ei   = (const int*)d_in[1];
  const float* W1l  = (const float*)d_in[2];
  const float* W1r  = (const float*)d_in[3];
  const float* att1 = (const float*)d_in[4];
  const float* b1   = (const float*)d_in[5];
  const float* W2l  = (const float*)d_in[6];
  const float* W2r  = (const float*)d_in[7];
  const float* att2 = (const float*)d_in[8];
  const float* b2   = (const float*)d_in[9];
  float* out = (float*)d_out;

  // Workspace layout (~79.3 MB):
  unsigned short* xlh = (unsigned short*)d_ws;        // [8][NN][32] fp16
  unsigned short* xrh = xlh + (size_t)NN * D1;        // [8][NN][32] fp16
  unsigned short* hb  = xrh + (size_t)NN * D1;        // [NN][256] fp16
  int* deg  = (int*)(hb + (size_t)NN * D1);           // NN (becomes cursor)
  int* part = deg + NN;                               // NB
  int* offs = part + NB;                              // NN+1 (+1 pad for align)
  uint2* ninfo = (uint2*)(offs + NN + 2);             // NN {beg, n|deg<<16}
  unsigned short* csr = (unsigned short*)(ninfo + NN);  // ET u16
  unsigned short* wt  = csr + ET + 2;                 // 512*128 fp16
  unsigned short* wt2 = wt + 512 * F1;                // 32*256 fp16
  unsigned short* h2lh = xlh;                         // alias: xlh dead after agg1
  float* h2r = (float*)(h2lh + (size_t)NN * C2);

  hipMemsetAsync(deg, 0, NN * sizeof(int), stream);
  k_prep<<<288 + (ET + 255) / 256, 256, 0, stream>>>(
      W1l, W1r, W2l, W2r, ei, wt, wt2, deg);
  k_gemm1m<<<MPAD / 64, 256, 0, stream>>>(x, wt, xlh, xrh);
  k_scan_part<<<NB, 256, 0, stream>>>(deg, part);
  k_scan_apply<<<NB, 256, 0, stream>>>(deg, part, offs, ninfo, csr);
  k_scatter<<<(E0 + 255) / 256, 256, 0, stream>>>(ei, deg, csr);
  k_agg1<<<NBK1 * 8, 256, 0, stream>>>(xlh, xrh, hb, ninfo, csr, att1, b1);
  k_gemm2m<<<(NN + 127) / 128, 256, 0, stream>>>(hb, wt2, h2lh, h2r);
  k_agg2<<<NN / 4, 256, 0, stream>>>(h2lh, h2r, ninfo, csr, att2, b2, out);
}